// Round 1
// baseline (346.986 us; speedup 1.0000x reference)
//
#include <hip/hip_runtime.h>

#define S_DIM 256
#define N_HM 32
#define K_APP 16
#define HW (S_DIM * S_DIM)
#define LDS_PAD 260   // 260 mod 32 == 4: 2-way bank aliasing only (free)

// ---------------------------------------------------------------------------
// Kernel 1: one block per (b, h). Softmax over w of 32 raw rows, then
// partial[bh][n][k] = sum_w p[n][w] * x[k][w].
// ---------------------------------------------------------------------------
template <bool ATOMIC>
__global__ __launch_bounds__(256) void k1_softmax_pool(
    const float* __restrict__ x,     // [B,16,256,256]
    const float* __restrict__ raw,   // [B,32,256,256]
    float* __restrict__ outp)        // partial [4096][512] or av [B][512]
{
    __shared__ float p_lds[N_HM][LDS_PAD];
    __shared__ float x_lds[K_APP][LDS_PAD];

    const int tid  = threadIdx.x;
    const int b    = blockIdx.x >> 8;
    const int h    = blockIdx.x & 255;
    const int wid  = tid >> 6;
    const int lane = tid & 63;

    // ---- stage global -> LDS (float4, fully coalesced; wave = one row) ----
    {
        const int c4 = lane;            // float4 column 0..63
        const float* basep = raw + ((size_t)(b * N_HM) << 16) + (h << 8);
        #pragma unroll
        for (int it = 0; it < 8; ++it) {
            int n = it * 4 + wid;
            float4 v = *(const float4*)(basep + ((size_t)n << 16) + (c4 << 2));
            *(float4*)&p_lds[n][c4 << 2] = v;
        }
        const float* basex = x + ((size_t)(b * K_APP) << 16) + (h << 8);
        #pragma unroll
        for (int it = 0; it < 4; ++it) {
            int k = it * 4 + wid;
            float4 v = *(const float4*)(basex + ((size_t)k << 16) + (c4 << 2));
            *(float4*)&x_lds[k][c4 << 2] = v;
        }
    }
    __syncthreads();

    // ---- per-row softmax over w; wave wid owns rows wid*8 .. wid*8+7 ----
    #pragma unroll
    for (int i = 0; i < 8; ++i) {
        int n = wid * 8 + i;
        float4 v = *(const float4*)&p_lds[n][lane << 2];
        float m = fmaxf(fmaxf(v.x, v.y), fmaxf(v.z, v.w));
        #pragma unroll
        for (int off = 32; off > 0; off >>= 1) m = fmaxf(m, __shfl_xor(m, off));
        float e0 = __expf(v.x - m), e1 = __expf(v.y - m);
        float e2 = __expf(v.z - m), e3 = __expf(v.w - m);
        float s = e0 + e1 + e2 + e3;
        #pragma unroll
        for (int off = 32; off > 0; off >>= 1) s += __shfl_xor(s, off);
        float inv = 1.0f / s;
        *(float4*)&p_lds[n][lane << 2] = make_float4(e0 * inv, e1 * inv, e2 * inv, e3 * inv);
    }
    __syncthreads();

    // ---- register-tiled 32x256x16 micro-GEMM ----
    // wave covers 4 n-tiles x 2 k-tiles; 8 chunks (c) partition w as {4c+32j}.
    const int wt = (tid >> 3) & 7;
    const int c  = tid & 7;
    const int n0 = (((wid >> 1) * 4) + (wt & 3)) * 4;
    const int k0 = (((wid & 1) * 2) + (wt >> 2)) * 4;

    float acc[4][4];
    #pragma unroll
    for (int i = 0; i < 4; ++i)
        #pragma unroll
        for (int j = 0; j < 4; ++j) acc[i][j] = 0.0f;

    #pragma unroll
    for (int j = 0; j < 8; ++j) {
        const int w = (c << 2) + (j << 5);
        float4 pv[4], xv[4];
        #pragma unroll
        for (int i = 0; i < 4; ++i) pv[i] = *(const float4*)&p_lds[n0 + i][w];
        #pragma unroll
        for (int i = 0; i < 4; ++i) xv[i] = *(const float4*)&x_lds[k0 + i][w];
        #pragma unroll
        for (int i = 0; i < 4; ++i)
            #pragma unroll
            for (int jj = 0; jj < 4; ++jj)
                acc[i][jj] += pv[i].x * xv[jj].x + pv[i].y * xv[jj].y +
                              pv[i].z * xv[jj].z + pv[i].w * xv[jj].w;
    }

    // reduce over the 8 w-chunks (contiguous 8-lane groups)
    #pragma unroll
    for (int off = 4; off > 0; off >>= 1)
        #pragma unroll
        for (int i = 0; i < 4; ++i)
            #pragma unroll
            for (int jj = 0; jj < 4; ++jj)
                acc[i][jj] += __shfl_down(acc[i][jj], off, 8);

    if (c == 0) {
        if (ATOMIC) {
            float* av = outp + (b << 9);
            #pragma unroll
            for (int i = 0; i < 4; ++i)
                #pragma unroll
                for (int jj = 0; jj < 4; ++jj)
                    atomicAdd(&av[(n0 + i) * 16 + k0 + jj], acc[i][jj]);
        } else {
            float* dst = outp + ((size_t)blockIdx.x << 9);
            #pragma unroll
            for (int i = 0; i < 4; ++i)
                *(float4*)(dst + (n0 + i) * 16 + k0) =
                    make_float4(acc[i][0], acc[i][1], acc[i][2], acc[i][3]);
        }
    }
}

// ---------------------------------------------------------------------------
// Kernel 1b: reduce 256 h-partials -> av[b][n][k]  (8192 outputs)
// ---------------------------------------------------------------------------
__global__ __launch_bounds__(256) void k1_reduce(
    const float* __restrict__ partial, float* __restrict__ av)
{
    const int gid = blockIdx.x * 256 + threadIdx.x;   // < 8192
    const int b = gid >> 9;
    const int r = gid & 511;
    const float* p = partial + ((size_t)(b << 8) << 9) + r;
    float s = 0.0f;
    #pragma unroll 8
    for (int h = 0; h < 256; ++h) s += p[(size_t)h << 9];
    av[gid] = s;
}

// ---------------------------------------------------------------------------
// Kernel 2: out[b,k,h,w] = (sum_n fit[b,n,h,w]*av[b,n,k]) / (1+sum_n fit)
// one thread per (b,h,w)
// ---------------------------------------------------------------------------
__global__ __launch_bounds__(256) void k2_combine(
    const float* __restrict__ fit,   // [B,32,256,256]
    const float* __restrict__ av,    // [B,32,16]
    float* __restrict__ out)         // [B,16,256,256]
{
    const int tid = threadIdx.x;
    const int b   = blockIdx.x >> 8;
    const int hw  = ((blockIdx.x & 255) << 8) + tid;

    const float* avb = av + (b << 9);                       // block-uniform
    const float* fb  = fit + ((size_t)(b * N_HM) << 16) + hw;

    float num[16];
    #pragma unroll
    for (int k = 0; k < 16; ++k) num[k] = 0.0f;
    float den = 1.0f;

    #pragma unroll 4
    for (int n = 0; n < 32; ++n) {
        float f = fb[(size_t)n << 16];
        den += f;
        const float4* ar = (const float4*)(avb + (n << 4)); // uniform -> s_load
        float4 a0 = ar[0], a1 = ar[1], a2 = ar[2], a3 = ar[3];
        num[0]  += f * a0.x;  num[1]  += f * a0.y;  num[2]  += f * a0.z;  num[3]  += f * a0.w;
        num[4]  += f * a1.x;  num[5]  += f * a1.y;  num[6]  += f * a1.z;  num[7]  += f * a1.w;
        num[8]  += f * a2.x;  num[9]  += f * a2.y;  num[10] += f * a2.z;  num[11] += f * a2.w;
        num[12] += f * a3.x;  num[13] += f * a3.y;  num[14] += f * a3.z;  num[15] += f * a3.w;
    }

    const float inv = 1.0f / den;
    float* ob = out + ((size_t)(b * K_APP) << 16) + hw;
    #pragma unroll
    for (int k = 0; k < 16; ++k) ob[(size_t)k << 16] = num[k] * inv;
}

// ---------------------------------------------------------------------------
extern "C" void kernel_launch(void* const* d_in, const int* in_sizes, int n_in,
                              void* d_out, int out_size, void* d_ws, size_t ws_size,
                              hipStream_t stream)
{
    const float* x   = (const float*)d_in[0];   // [16,16,256,256]
    const float* raw = (const float*)d_in[1];   // [16,32,256,256]
    const float* fit = (const float*)d_in[2];   // [16,32,256,256]
    float* out = (float*)d_out;

    float* av      = (float*)d_ws;              // 8192 floats (32 KB)
    float* partial = (float*)d_ws + 8192;       // 4096*512 floats (8 MB)
    const size_t need = (size_t)(8192 + 4096 * 512) * sizeof(float);

    const int nblk = 16 * S_DIM;                // 4096 = B*S

    if (ws_size >= need) {
        k1_softmax_pool<false><<<nblk, 256, 0, stream>>>(x, raw, partial);
        k1_reduce<<<8192 / 256, 256, 0, stream>>>(partial, av);
    } else {
        hipMemsetAsync(av, 0, 8192 * sizeof(float), stream);
        k1_softmax_pool<true><<<nblk, 256, 0, stream>>>(x, raw, av);
    }
    k2_combine<<<nblk, 256, 0, stream>>>(fit, av, out);
}